// Round 8
// baseline (393.122 us; speedup 1.0000x reference)
//
#include <hip/hip_runtime.h>
#include <math.h>

#define Lc 4096
#define Hc 1024
#define Bc 4
#define NNc 32

typedef __attribute__((ext_vector_type(8))) short s8v;
typedef __attribute__((ext_vector_type(4))) float f4v;

// swizzled element index for [64][64] bf16 matrix (rows 128B): XOR 16B slot by row&7
#define SWB(r, e) ((((r) << 6) + (e)) ^ (((r) & 7) << 3))

__device__ inline unsigned short bf16_rne(float x) {
    unsigned u = __float_as_uint(x);
    unsigned r = (u + 0x7FFFu + ((u >> 16) & 1u)) >> 16;
    return (unsigned short)r;
}
__device__ inline void split2(float x, unsigned short* h, unsigned short* l) {
    unsigned short hb = bf16_rne(x);
    *h = hb;
    float hf = __uint_as_float(((unsigned)hb) << 16);
    *l = bf16_rne(x - hf);
}

// K1: x [B][L][H] fp32 -> X-hi plane bf16 [B][H][4096]
__global__ __launch_bounds__(256) void split_transpose(const float* __restrict__ src,
                                                       unsigned short* __restrict__ dst) {
    __shared__ float tile[64][65];
    int b  = blockIdx.z;
    int h0 = blockIdx.x * 64;
    int l0 = blockIdx.y * 64;
    const float* s = src + (size_t)b * Lc * Hc;
    int tid = threadIdx.x;
#pragma unroll
    for (int it = 0; it < 4; it++) {
        int idx = tid + 256 * it;
        int r = idx >> 4, c4 = idx & 15;            // r = l-row, c4 = h-quad
        float4 v = *(const float4*)(s + (size_t)(l0 + r) * Hc + (h0 + 4 * c4));
        tile[r][4 * c4 + 0] = v.x;
        tile[r][4 * c4 + 1] = v.y;
        tile[r][4 * c4 + 2] = v.z;
        tile[r][4 * c4 + 3] = v.w;
    }
    __syncthreads();
#pragma unroll
    for (int it = 0; it < 8; it++) {
        int hh = it * 8 + (tid >> 5);               // h within tile
        int p  = tid & 31;                          // l-pair within tile
        float v0 = tile[2 * p + 0][hh];
        float v1 = tile[2 * p + 1][hh];
        unsigned hi = (unsigned)bf16_rne(v0) | ((unsigned)bf16_rne(v1) << 16);
        unsigned short* base = dst + (size_t)(b * Hc + h0 + hh) * 4096;
        *(unsigned*)(base + (l0 + 2 * p)) = hi;
    }
}

// K3: yT bf16 [B][H][L] -> out [B][L][H] fp32
__global__ __launch_bounds__(256) void untranspose_bf16(const unsigned short* __restrict__ src,
                                                        float* __restrict__ dst) {
    __shared__ float tile[64][65];   // [h_local][l_local]
    int b  = blockIdx.z;
    int h0 = blockIdx.x * 64;
    int l0 = blockIdx.y * 64;
    const unsigned short* s = src + (size_t)b * Hc * Lc;
    float* d = dst + (size_t)b * Lc * Hc;
    int tid = threadIdx.x;
#pragma unroll
    for (int it = 0; it < 8; it++) {
        int idx = tid + 256 * it;                  // 2048 dwords
        int hh = idx >> 5, dp = idx & 31;
        unsigned v = *(const unsigned*)(s + (size_t)(h0 + hh) * Lc + (l0 + 2 * dp));
        tile[hh][2 * dp]     = __uint_as_float((v & 0xffffu) << 16);
        tile[hh][2 * dp + 1] = __uint_as_float((v >> 16) << 16);
    }
    __syncthreads();
#pragma unroll
    for (int it = 0; it < 4; it++) {
        int idx = tid + 256 * it;
        int r = idx >> 4, c4 = idx & 15;           // r = l_local, c4 = h-quad
        f4v v;
        v.x = tile[4 * c4 + 0][r];
        v.y = tile[4 * c4 + 1][r];
        v.z = tile[4 * c4 + 2][r];
        v.w = tile[4 * c4 + 3][r];
        __builtin_nontemporal_store(v, (f4v*)(d + (size_t)(l0 + r) * Hc + (h0 + 4 * c4)));
    }
}

#define MFMA(a, b, c) __builtin_amdgcn_mfma_f32_16x16x32_bf16((a), (b), (c), 0, 0, 0)

// One block per h; 4 batches. Reads X-hi plane, writes Y bf16 plane.
__global__ __launch_bounds__(256, 4) void s4d_mfma6(
    const unsigned short* __restrict__ xpl,
    unsigned short* __restrict__ ypl,
    const float* __restrict__ log_dt,
    const float* __restrict__ log_A_real,
    const float* __restrict__ A_imag,
    const float* __restrict__ Cmat,
    const float* __restrict__ Dvec)
{
    __shared__ __align__(16) unsigned short WtH[4096];   // S = X*Wrev (hi)
    __shared__ float Sscan[64 * 65];   // [mode-comp][chunk]; Kpart scratch; Y staging
    __shared__ float Ktap[64];
    __shared__ float cAr[NNc], cAi[NNc], c2R[NNc], c2I[NNc], cWSr[NNc], cWSi[NNc];

    const int tid = threadIdx.x;
    const int h   = blockIdx.x;
    const int w   = tid >> 6;
    const int l   = tid & 63;
    const int l15 = l & 15;
    const int grp = l >> 4;
    const int rowoff = (16 * w + l15) * 64;

    // early X frag load for b=0 (hides under table generation)
    s8v xh0, xh1;
    {
        const unsigned short* xb = xpl + (size_t)h * 4096;
        xh0 = *(const s8v*)(xb + rowoff + 8 * grp);
        xh1 = *(const s8v*)(xb + rowoff + 32 + 8 * grp);
    }

    // ---- per-mode constants (PRECISE: w^64 errors compound x63 in the scan) ----
    if (tid < NNc) {
        int n = tid;
        float dtv = expf(log_dt[h]);
        float Ar = -expf(log_A_real[h * NNc + n]);
        float Ai = A_imag[h * NNc + n];
        float ar = Ar * dtv, ai = Ai * dtv;
        cAr[n] = ar; cAi[n] = ai;
        float er = expf(ar), sn, cs;
        sincosf(ai, &sn, &cs);
        float numr = er * cs - 1.f, numi = er * sn;
        float inv = 1.f / (Ar * Ar + Ai * Ai);
        float fr = (numr * Ar + numi * Ai) * inv;
        float fi = (numi * Ar - numr * Ai) * inv;
        float Ccr = Cmat[(h * NNc + n) * 2 + 0];
        float Cci = Cmat[(h * NNc + n) * 2 + 1];
        c2R[n] = 2.f * (Ccr * fr - Cci * fi);
        c2I[n] = 2.f * (Ccr * fi + Cci * fr);
        float e64 = expf(64.f * ar), s64, c64;
        sincosf(64.f * ai, &s64, &c64);
        cWSr[n] = e64 * c64; cWSi[n] = e64 * s64;   // w^64
    }
    __syncthreads();

    // ---- Kpart (into Sscan scratch) + Wt table gen (fast intrinsics) ----
    {
        int p = tid >> 2, q = tid & 3;
        float acc = 0.f;
#pragma unroll
        for (int i = 0; i < 8; i++) {
            int n = 8 * q + i;
            float fp = (float)p;
            float e = __expf(cAr[n] * fp);
            float sn = __sinf(cAi[n] * fp), cs = __cosf(cAi[n] * fp);
            acc += e * (c2R[n] * cs - c2I[n] * sn);
        }
        Sscan[p * 4 + q] = acc;
    }
#pragma unroll
    for (int m = 0; m < 2; m++) {
        int u = tid + 256 * m;
        int r = u >> 3, jc = u & 7;
        // Wt row r = out mode-comp: w_n^{63-j} (hi only)
        int n = r >> 1, im = r & 1;
        s8v hv;
#pragma unroll
        for (int i = 0; i < 8; i++) {
            float p = (float)(63 - (jc * 8 + i));
            float e = __expf(cAr[n] * p);
            float sn = __sinf(cAi[n] * p), cs = __cosf(cAi[n] * p);
            hv[i] = (short)bf16_rne(e * (im ? sn : cs));
        }
        *(s8v*)&WtH[SWB(r, jc * 8)] = hv;
    }
    __syncthreads();

    if (tid < 64) {
        float k = Sscan[tid * 4] + Sscan[tid * 4 + 1] + Sscan[tid * 4 + 2] + Sscan[tid * 4 + 3];
        if (tid == 0) k += Dvec[h];
        Ktap[tid] = k;
    }
    __syncthreads();

    // ---- Toeplitz B-fragments: batch-invariant -> registers (8 x s8v) ----
    s8v tf[4][2];
#pragma unroll
    for (int tj = 0; tj < 4; tj++) {
        int row = tj * 16 + l15;
#pragma unroll
        for (int hf = 0; hf < 2; hf++) {
            int kb = 32 * hf + 8 * grp;
            s8v v;
#pragma unroll
            for (int i = 0; i < 8; i++) {
                int idx = row - kb - i;
                int ic = idx < 0 ? 0 : idx;
                float kv = Ktap[ic];
                v[i] = (short)bf16_rne(idx < 0 ? 0.f : kv);
            }
            tf[tj][hf] = v;
        }
    }

    // ---- Wp B-fragments (carry powers): batch-invariant -> registers (8 x s8v) ----
    // wp[tj][hf][i] = Re/-Im( w_n^{t+1} ),  t = tj*16+l15,  c = 32*hf+8*grp+i, n = c>>1
    s8v wp[4][2];
#pragma unroll
    for (int tj = 0; tj < 4; tj++) {
        float fp = (float)(tj * 16 + l15 + 1);
#pragma unroll
        for (int hf = 0; hf < 2; hf++) {
            s8v v;
#pragma unroll
            for (int i = 0; i < 8; i++) {
                int c = 32 * hf + 8 * grp + i;
                int n = c >> 1;
                float e = __expf(cAr[n] * fp);
                float sn = __sinf(cAi[n] * fp), cs = __cosf(cAi[n] * fp);
                v[i] = (short)bf16_rne(e * ((c & 1) ? -sn : cs));
            }
            wp[tj][hf] = v;
        }
    }

    // ---- batch loop ----
#pragma unroll
    for (int b = 0; b < Bc; b++) {
        // prefetch next batch's X fragments
        s8v nh0, nh1;
        if (b < Bc - 1) {
            const unsigned short* xb = xpl + (size_t)((b + 1) * Hc + h) * 4096;
            nh0 = *(const s8v*)(xb + rowoff + 8 * grp);
            nh1 = *(const s8v*)(xb + rowoff + 32 + 8 * grp);
        }

        // Phase 1: S = X * Wrev. D rows = chunk s, cols = mode-comp m.
        f4v acc[4];
#pragma unroll
        for (int tj = 0; tj < 4; tj++) {
            int row = tj * 16 + l15;
            int i0 = SWB(row, 8 * grp);
            int i1 = SWB(row, 32 + 8 * grp);
            s8v bh0 = *(const s8v*)&WtH[i0];
            s8v bh1 = *(const s8v*)&WtH[i1];
            f4v a = {0.f, 0.f, 0.f, 0.f};
            a = MFMA(xh0, bh0, a);
            a = MFMA(xh1, bh1, a);
            acc[tj] = a;
        }
        // store S transposed: Sscan[m][s]
#pragma unroll
        for (int tj = 0; tj < 4; tj++) {
#pragma unroll
            for (int r2 = 0; r2 < 4; r2++) {
                Sscan[(tj * 16 + l15) * 65 + 16 * w + 4 * grp + r2] = acc[tj][r2];
            }
        }
        __syncthreads();   // (a)

        // ---- wave-parallel Kogge-Stone scan: wave w owns modes 8w..8w+7, lane = chunk ----
        {
            float Pr[8], Pi[8], qr[8], qi[8];
#pragma unroll
            for (int i = 0; i < 8; i++) {
                int m0 = (16 * w + 2 * i) * 65;
                Pr[i] = Sscan[m0 + l];
                Pi[i] = Sscan[m0 + 65 + l];
                int n = 8 * w + i;
                qr[i] = cWSr[n]; qi[i] = cWSi[n];
            }
#pragma unroll
            for (int d = 1; d < 64; d <<= 1) {
#pragma unroll
                for (int i = 0; i < 8; i++) {
                    float tr = __shfl_up(Pr[i], (unsigned)d, 64);
                    float ti = __shfl_up(Pi[i], (unsigned)d, 64);
                    if (l >= d) {
                        Pr[i] = fmaf(qr[i], tr, fmaf(-qi[i], ti, Pr[i]));
                        Pi[i] = fmaf(qr[i], ti, fmaf( qi[i], tr, Pi[i]));
                    }
                }
                if (d < 32) {
#pragma unroll
                    for (int i = 0; i < 8; i++) {
                        float nr = fmaf(qr[i], qr[i], -(qi[i] * qi[i]));
                        float ni = 2.f * qr[i] * qi[i];
                        qr[i] = nr; qi[i] = ni;
                    }
                }
            }
            // G_s = P_{s-1}; E = 2Cw (x) G
#pragma unroll
            for (int i = 0; i < 8; i++) {
                float Gr = __shfl_up(Pr[i], 1u, 64);
                float Gi = __shfl_up(Pi[i], 1u, 64);
                if (l == 0) { Gr = 0.f; Gi = 0.f; }
                int n = 8 * w + i;
                float cr = c2R[n], ci = c2I[n];
                float er = fmaf(cr, Gr, -(ci * Gi));
                float ei = fmaf(cr, Gi,  (ci * Gr));
                int m0 = (16 * w + 2 * i) * 65;
                Sscan[m0 + l]      = er;
                Sscan[m0 + 65 + l] = ei;
            }
        }
        __syncthreads();   // (b)

        // E fragments: A rows = chunk 16w+l15, k = mode-comp
        s8v eh0, el0, eh1, el1;
        {
            float ev[16];
#pragma unroll
            for (int i = 0; i < 8; i++)
                ev[i] = Sscan[(8 * grp + i) * 65 + 16 * w + l15];
#pragma unroll
            for (int i = 0; i < 8; i++)
                ev[8 + i] = Sscan[(32 + 8 * grp + i) * 65 + 16 * w + l15];
#pragma unroll
            for (int i = 0; i < 8; i++) {
                unsigned short hh, ll;
                split2(ev[i], &hh, &ll);
                eh0[i] = (short)hh; el0[i] = (short)ll;
                split2(ev[8 + i], &hh, &ll);
                eh1[i] = (short)hh; el1[i] = (short)ll;
            }
        }
        __syncthreads();   // (c) — Sscan free for Y staging

        // Phase 3: Y = X*T + E*Wp -> stage fp32 into Sscan[s][t]
#pragma unroll
        for (int tj = 0; tj < 4; tj++) {
            f4v a = {0.f, 0.f, 0.f, 0.f};
            a = MFMA(xh0, tf[tj][0], a);
            a = MFMA(xh1, tf[tj][1], a);
            a = MFMA(eh0, wp[tj][0], a);
            a = MFMA(eh1, wp[tj][1], a);
            a = MFMA(el0, wp[tj][0], a);
            a = MFMA(el1, wp[tj][1], a);
#pragma unroll
            for (int r2 = 0; r2 < 4; r2++) {
                Sscan[(16 * w + 4 * grp + r2) * 65 + tj * 16 + l15] = a[r2];
            }
        }
        __syncthreads();   // (d) — Y tile complete in LDS

        // stream Y out as bf16: 8 x coalesced dword stores (64 l-pairs per row)
        {
            unsigned short* yp = ypl + (size_t)(b * Hc + h) * 4096;
#pragma unroll
            for (int i = 0; i < 8; i++) {
                int p = tid + 256 * i;              // dword index 0..2047
                int s = p >> 5, tp = p & 31;
                float v0 = Sscan[s * 65 + 2 * tp];
                float v1 = Sscan[s * 65 + 2 * tp + 1];
                unsigned pk = (unsigned)bf16_rne(v0) | ((unsigned)bf16_rne(v1) << 16);
                *(unsigned*)(yp + 2 * p) = pk;
            }
        }
        __syncthreads();   // (e) — Sscan free for next batch

        if (b < Bc - 1) { xh0 = nh0; xh1 = nh1; }
    }
}

extern "C" void kernel_launch(void* const* d_in, const int* in_sizes, int n_in,
                              void* d_out, int out_size, void* d_ws, size_t ws_size,
                              hipStream_t stream) {
    const float* x          = (const float*)d_in[0];
    const float* log_dt     = (const float*)d_in[1];
    const float* log_A_real = (const float*)d_in[2];
    const float* A_imag     = (const float*)d_in[3];
    const float* Cmat       = (const float*)d_in[4];
    const float* Dvec       = (const float*)d_in[5];
    float* out = (float*)d_out;

    const size_t plane = (size_t)Bc * Hc * Lc;            // elements (bf16)
    const size_t need  = plane * 2 * sizeof(unsigned short);  // X + Y planes = 64 MiB
    if (ws_size < need) return;

    unsigned short* xpl = (unsigned short*)d_ws;
    unsigned short* ypl = xpl + plane;

    // x [B][L][H] -> X-hi bf16 plane [B][H][L]
    split_transpose<<<dim3(Hc / 64, Lc / 64, Bc), 256, 0, stream>>>(x, xpl);
    // fused SSM per h (all batches); writes Y bf16 plane [B][H][L]
    s4d_mfma6<<<Hc, 256, 0, stream>>>(xpl, ypl, log_dt, log_A_real, A_imag, Cmat, Dvec);
    // Y bf16 [B][H][L] -> out fp32 [B][L][H]
    untranspose_bf16<<<dim3(Hc / 64, Lc / 64, Bc), 256, 0, stream>>>(ypl, out);
}

// Round 9
// 99.607 us; speedup vs baseline: 3.9467x; 3.9467x over previous
//
#include <hip/hip_runtime.h>
#include <math.h>

#define Lc 4096
#define Hc 1024
#define Bc 4
#define NNc 32

typedef __attribute__((ext_vector_type(8))) short s8v;
typedef __attribute__((ext_vector_type(4))) float f4v;

// swizzled element index for [64][64] bf16 matrix (rows 128B): XOR 16B slot by row&7
#define SWB(r, e) ((((r) << 6) + (e)) ^ (((r) & 7) << 3))

__device__ inline unsigned short bf16_rne(float x) {
    unsigned u = __float_as_uint(x);
    unsigned r = (u + 0x7FFFu + ((u >> 16) & 1u)) >> 16;
    return (unsigned short)r;
}
__device__ inline void split2(float x, unsigned short* h, unsigned short* l) {
    unsigned short hb = bf16_rne(x);
    *h = hb;
    float hf = __uint_as_float(((unsigned)hb) << 16);
    *l = bf16_rne(x - hf);
}

// K1: x [B][L][H] fp32 -> X-hi plane bf16 [B][H][4096]
__global__ __launch_bounds__(256) void split_transpose(const float* __restrict__ src,
                                                       unsigned short* __restrict__ dst) {
    __shared__ float tile[64][65];
    int b  = blockIdx.z;
    int h0 = blockIdx.x * 64;
    int l0 = blockIdx.y * 64;
    const float* s = src + (size_t)b * Lc * Hc;
    int tid = threadIdx.x;
#pragma unroll
    for (int it = 0; it < 4; it++) {
        int idx = tid + 256 * it;
        int r = idx >> 4, c4 = idx & 15;            // r = l-row, c4 = h-quad
        float4 v = *(const float4*)(s + (size_t)(l0 + r) * Hc + (h0 + 4 * c4));
        tile[r][4 * c4 + 0] = v.x;
        tile[r][4 * c4 + 1] = v.y;
        tile[r][4 * c4 + 2] = v.z;
        tile[r][4 * c4 + 3] = v.w;
    }
    __syncthreads();
#pragma unroll
    for (int it = 0; it < 8; it++) {
        int hh = it * 8 + (tid >> 5);               // h within tile
        int p  = tid & 31;                          // l-pair within tile
        float v0 = tile[2 * p + 0][hh];
        float v1 = tile[2 * p + 1][hh];
        unsigned hi = (unsigned)bf16_rne(v0) | ((unsigned)bf16_rne(v1) << 16);
        unsigned short* base = dst + (size_t)(b * Hc + h0 + hh) * 4096;
        *(unsigned*)(base + (l0 + 2 * p)) = hi;
    }
}

// K3: yT bf16 [B][H][L] -> out [B][L][H] fp32
__global__ __launch_bounds__(256) void untranspose_bf16(const unsigned short* __restrict__ src,
                                                        float* __restrict__ dst) {
    __shared__ float tile[64][65];   // [h_local][l_local]
    int b  = blockIdx.z;
    int h0 = blockIdx.x * 64;
    int l0 = blockIdx.y * 64;
    const unsigned short* s = src + (size_t)b * Hc * Lc;
    float* d = dst + (size_t)b * Lc * Hc;
    int tid = threadIdx.x;
#pragma unroll
    for (int it = 0; it < 8; it++) {
        int idx = tid + 256 * it;                  // 2048 dwords
        int hh = idx >> 5, dp = idx & 31;
        unsigned v = *(const unsigned*)(s + (size_t)(h0 + hh) * Lc + (l0 + 2 * dp));
        tile[hh][2 * dp]     = __uint_as_float((v & 0xffffu) << 16);
        tile[hh][2 * dp + 1] = __uint_as_float((v >> 16) << 16);
    }
    __syncthreads();
#pragma unroll
    for (int it = 0; it < 4; it++) {
        int idx = tid + 256 * it;
        int r = idx >> 4, c4 = idx & 15;           // r = l_local, c4 = h-quad
        f4v v;
        v.x = tile[4 * c4 + 0][r];
        v.y = tile[4 * c4 + 1][r];
        v.z = tile[4 * c4 + 2][r];
        v.w = tile[4 * c4 + 3][r];
        __builtin_nontemporal_store(v, (f4v*)(d + (size_t)(l0 + r) * Hc + (h0 + 4 * c4)));
    }
}

#define MFMA(a, b, c) __builtin_amdgcn_mfma_f32_16x16x32_bf16((a), (b), (c), 0, 0, 0)

// One block per h; 4 batches. Reads X-hi plane, writes Y bf16 plane.
// Wp kept in LDS (NOT registers) to stay under the 128-VGPR/(256,4) budget.
__global__ __launch_bounds__(256, 4) void s4d_mfma7(
    const unsigned short* __restrict__ xpl,
    unsigned short* __restrict__ ypl,
    const float* __restrict__ log_dt,
    const float* __restrict__ log_A_real,
    const float* __restrict__ A_imag,
    const float* __restrict__ Cmat,
    const float* __restrict__ Dvec)
{
    __shared__ __align__(16) unsigned short WtH[4096];   // S = X*Wrev (hi)
    __shared__ __align__(16) unsigned short WpH[4096];   // carry powers (hi)
    __shared__ float Sscan[64 * 65];   // [mode-comp][chunk]; Kpart scratch; Y staging
    __shared__ float Ktap[64];
    __shared__ float cAr[NNc], cAi[NNc], c2R[NNc], c2I[NNc], cWSr[NNc], cWSi[NNc];

    const int tid = threadIdx.x;
    const int h   = blockIdx.x;
    const int w   = tid >> 6;
    const int l   = tid & 63;
    const int l15 = l & 15;
    const int grp = l >> 4;
    const int rowoff = (16 * w + l15) * 64;

    // early X frag load for b=0 (hides under table generation)
    s8v xh0, xh1;
    {
        const unsigned short* xb = xpl + (size_t)h * 4096;
        xh0 = *(const s8v*)(xb + rowoff + 8 * grp);
        xh1 = *(const s8v*)(xb + rowoff + 32 + 8 * grp);
    }

    // ---- per-mode constants (PRECISE: w^64 errors compound x63 in the scan) ----
    if (tid < NNc) {
        int n = tid;
        float dtv = expf(log_dt[h]);
        float Ar = -expf(log_A_real[h * NNc + n]);
        float Ai = A_imag[h * NNc + n];
        float ar = Ar * dtv, ai = Ai * dtv;
        cAr[n] = ar; cAi[n] = ai;
        float er = expf(ar), sn, cs;
        sincosf(ai, &sn, &cs);
        float numr = er * cs - 1.f, numi = er * sn;
        float inv = 1.f / (Ar * Ar + Ai * Ai);
        float fr = (numr * Ar + numi * Ai) * inv;
        float fi = (numi * Ar - numr * Ai) * inv;
        float Ccr = Cmat[(h * NNc + n) * 2 + 0];
        float Cci = Cmat[(h * NNc + n) * 2 + 1];
        c2R[n] = 2.f * (Ccr * fr - Cci * fi);
        c2I[n] = 2.f * (Ccr * fi + Cci * fr);
        float e64 = expf(64.f * ar), s64, c64;
        sincosf(64.f * ai, &s64, &c64);
        cWSr[n] = e64 * c64; cWSi[n] = e64 * s64;   // w^64
    }
    __syncthreads();

    // ---- Kpart (into Sscan scratch) + Wt + Wp generation (fast intrinsics) ----
    {
        int p = tid >> 2, q = tid & 3;
        float acc = 0.f;
#pragma unroll
        for (int i = 0; i < 8; i++) {
            int n = 8 * q + i;
            float fp = (float)p;
            float e = __expf(cAr[n] * fp);
            float sn = __sinf(cAi[n] * fp), cs = __cosf(cAi[n] * fp);
            acc += e * (c2R[n] * cs - c2I[n] * sn);
        }
        Sscan[p * 4 + q] = acc;
    }
#pragma unroll
    for (int m = 0; m < 2; m++) {
        int u = tid + 256 * m;
        int r = u >> 3, jc = u & 7;
        {   // Wt row r = out mode-comp: w_n^{63-j} (hi only)
            int n = r >> 1, im = r & 1;
            s8v hv;
#pragma unroll
            for (int i = 0; i < 8; i++) {
                float p = (float)(63 - (jc * 8 + i));
                float e = __expf(cAr[n] * p);
                float sn = __sinf(cAi[n] * p), cs = __cosf(cAi[n] * p);
                hv[i] = (short)bf16_rne(e * (im ? sn : cs));
            }
            *(s8v*)&WtH[SWB(r, jc * 8)] = hv;
        }
        {   // Wp row r = t: col c: Re(w^{t+1}) / -Im(w^{t+1})  (hi only)
            float p = (float)(r + 1);
            s8v hv;
#pragma unroll
            for (int i = 0; i < 8; i++) {
                int c = jc * 8 + i;
                int n = c >> 1;
                float e = __expf(cAr[n] * p);
                float sn = __sinf(cAi[n] * p), cs = __cosf(cAi[n] * p);
                hv[i] = (short)bf16_rne(e * ((c & 1) ? -sn : cs));
            }
            *(s8v*)&WpH[SWB(r, jc * 8)] = hv;
        }
    }
    __syncthreads();

    if (tid < 64) {
        float k = Sscan[tid * 4] + Sscan[tid * 4 + 1] + Sscan[tid * 4 + 2] + Sscan[tid * 4 + 3];
        if (tid == 0) k += Dvec[h];
        Ktap[tid] = k;
    }
    __syncthreads();

    // ---- Toeplitz B-fragments: batch-invariant -> registers (8 x s8v) ----
    s8v tf[4][2];
#pragma unroll
    for (int tj = 0; tj < 4; tj++) {
        int row = tj * 16 + l15;
#pragma unroll
        for (int hf = 0; hf < 2; hf++) {
            int kb = 32 * hf + 8 * grp;
            s8v v;
#pragma unroll
            for (int i = 0; i < 8; i++) {
                int idx = row - kb - i;
                int ic = idx < 0 ? 0 : idx;
                float kv = Ktap[ic];
                v[i] = (short)bf16_rne(idx < 0 ? 0.f : kv);
            }
            tf[tj][hf] = v;
        }
    }

    // ---- batch loop ----
#pragma unroll
    for (int b = 0; b < Bc; b++) {
        // prefetch next batch's X fragments
        s8v nh0, nh1;
        if (b < Bc - 1) {
            const unsigned short* xb = xpl + (size_t)((b + 1) * Hc + h) * 4096;
            nh0 = *(const s8v*)(xb + rowoff + 8 * grp);
            nh1 = *(const s8v*)(xb + rowoff + 32 + 8 * grp);
        }

        // Phase 1: S = X * Wrev. D rows = chunk s, cols = mode-comp m.
        f4v acc[4];
#pragma unroll
        for (int tj = 0; tj < 4; tj++) {
            int row = tj * 16 + l15;
            int i0 = SWB(row, 8 * grp);
            int i1 = SWB(row, 32 + 8 * grp);
            s8v bh0 = *(const s8v*)&WtH[i0];
            s8v bh1 = *(const s8v*)&WtH[i1];
            f4v a = {0.f, 0.f, 0.f, 0.f};
            a = MFMA(xh0, bh0, a);
            a = MFMA(xh1, bh1, a);
            acc[tj] = a;
        }
        // store S transposed: Sscan[m][s]
#pragma unroll
        for (int tj = 0; tj < 4; tj++) {
#pragma unroll
            for (int r2 = 0; r2 < 4; r2++) {
                Sscan[(tj * 16 + l15) * 65 + 16 * w + 4 * grp + r2] = acc[tj][r2];
            }
        }
        __syncthreads();   // (a)

        // ---- wave-parallel Kogge-Stone scan: wave w owns modes 8w..8w+7, lane = chunk ----
        {
            float Pr[8], Pi[8], qr[8], qi[8];
#pragma unroll
            for (int i = 0; i < 8; i++) {
                int m0 = (16 * w + 2 * i) * 65;
                Pr[i] = Sscan[m0 + l];
                Pi[i] = Sscan[m0 + 65 + l];
                int n = 8 * w + i;
                qr[i] = cWSr[n]; qi[i] = cWSi[n];
            }
#pragma unroll
            for (int d = 1; d < 64; d <<= 1) {
#pragma unroll
                for (int i = 0; i < 8; i++) {
                    float tr = __shfl_up(Pr[i], (unsigned)d, 64);
                    float ti = __shfl_up(Pi[i], (unsigned)d, 64);
                    if (l >= d) {
                        Pr[i] = fmaf(qr[i], tr, fmaf(-qi[i], ti, Pr[i]));
                        Pi[i] = fmaf(qr[i], ti, fmaf( qi[i], tr, Pi[i]));
                    }
                }
                if (d < 32) {
#pragma unroll
                    for (int i = 0; i < 8; i++) {
                        float nr = fmaf(qr[i], qr[i], -(qi[i] * qi[i]));
                        float ni = 2.f * qr[i] * qi[i];
                        qr[i] = nr; qi[i] = ni;
                    }
                }
            }
            // G_s = P_{s-1}; E = 2Cw (x) G
#pragma unroll
            for (int i = 0; i < 8; i++) {
                float Gr = __shfl_up(Pr[i], 1u, 64);
                float Gi = __shfl_up(Pi[i], 1u, 64);
                if (l == 0) { Gr = 0.f; Gi = 0.f; }
                int n = 8 * w + i;
                float cr = c2R[n], ci = c2I[n];
                float er = fmaf(cr, Gr, -(ci * Gi));
                float ei = fmaf(cr, Gi,  (ci * Gr));
                int m0 = (16 * w + 2 * i) * 65;
                Sscan[m0 + l]      = er;
                Sscan[m0 + 65 + l] = ei;
            }
        }
        __syncthreads();   // (b)

        // E fragments: A rows = chunk 16w+l15, k = mode-comp
        s8v eh0, el0, eh1, el1;
        {
            float ev[16];
#pragma unroll
            for (int i = 0; i < 8; i++)
                ev[i] = Sscan[(8 * grp + i) * 65 + 16 * w + l15];
#pragma unroll
            for (int i = 0; i < 8; i++)
                ev[8 + i] = Sscan[(32 + 8 * grp + i) * 65 + 16 * w + l15];
#pragma unroll
            for (int i = 0; i < 8; i++) {
                unsigned short hh, ll;
                split2(ev[i], &hh, &ll);
                eh0[i] = (short)hh; el0[i] = (short)ll;
                split2(ev[8 + i], &hh, &ll);
                eh1[i] = (short)hh; el1[i] = (short)ll;
            }
        }
        __syncthreads();   // (c) — Sscan free for Y staging

        // Phase 3: Y = X*T + E*Wp -> stage fp32 into Sscan[s][t]
#pragma unroll
        for (int tj = 0; tj < 4; tj++) {
            int row = tj * 16 + l15;
            int i0 = SWB(row, 8 * grp);
            int i1 = SWB(row, 32 + 8 * grp);
            s8v ph0 = *(const s8v*)&WpH[i0];
            s8v ph1 = *(const s8v*)&WpH[i1];
            f4v a = {0.f, 0.f, 0.f, 0.f};
            a = MFMA(xh0, tf[tj][0], a);
            a = MFMA(xh1, tf[tj][1], a);
            a = MFMA(eh0, ph0, a);
            a = MFMA(eh1, ph1, a);
            a = MFMA(el0, ph0, a);
            a = MFMA(el1, ph1, a);
#pragma unroll
            for (int r2 = 0; r2 < 4; r2++) {
                Sscan[(16 * w + 4 * grp + r2) * 65 + tj * 16 + l15] = a[r2];
            }
        }
        __syncthreads();   // (d) — Y tile complete in LDS

        // stream Y out as bf16: 8 x coalesced dword stores
        {
            unsigned short* yp = ypl + (size_t)(b * Hc + h) * 4096;
#pragma unroll
            for (int i = 0; i < 8; i++) {
                int p = tid + 256 * i;              // dword index 0..2047
                int s = p >> 5, tp = p & 31;
                float v0 = Sscan[s * 65 + 2 * tp];
                float v1 = Sscan[s * 65 + 2 * tp + 1];
                unsigned pk = (unsigned)bf16_rne(v0) | ((unsigned)bf16_rne(v1) << 16);
                *(unsigned*)(yp + 2 * p) = pk;
            }
        }
        __syncthreads();   // (e) — Sscan free for next batch

        if (b < Bc - 1) { xh0 = nh0; xh1 = nh1; }
    }
}

extern "C" void kernel_launch(void* const* d_in, const int* in_sizes, int n_in,
                              void* d_out, int out_size, void* d_ws, size_t ws_size,
                              hipStream_t stream) {
    const float* x          = (const float*)d_in[0];
    const float* log_dt     = (const float*)d_in[1];
    const float* log_A_real = (const float*)d_in[2];
    const float* A_imag     = (const float*)d_in[3];
    const float* Cmat       = (const float*)d_in[4];
    const float* Dvec       = (const float*)d_in[5];
    float* out = (float*)d_out;

    const size_t plane = (size_t)Bc * Hc * Lc;                // elements (bf16)
    const size_t need  = plane * 2 * sizeof(unsigned short);  // X + Y planes = 64 MiB
    if (ws_size < need) return;

    unsigned short* xpl = (unsigned short*)d_ws;
    unsigned short* ypl = xpl + plane;

    // x [B][L][H] -> X-hi bf16 plane [B][H][L]
    split_transpose<<<dim3(Hc / 64, Lc / 64, Bc), 256, 0, stream>>>(x, xpl);
    // fused SSM per h (all batches); writes Y bf16 plane [B][H][L]
    s4d_mfma7<<<Hc, 256, 0, stream>>>(xpl, ypl, log_dt, log_A_real, A_imag, Cmat, Dvec);
    // Y bf16 [B][H][L] -> out fp32 [B][L][H]
    untranspose_bf16<<<dim3(Hc / 64, Lc / 64, Bc), 256, 0, stream>>>(ypl, out);
}

// Round 10
// 96.004 us; speedup vs baseline: 4.0948x; 1.0375x over previous
//
#include <hip/hip_runtime.h>
#include <math.h>

#define Lc 4096
#define Hc 1024
#define Bc 4
#define NNc 32

typedef __attribute__((ext_vector_type(8))) short s8v;
typedef __attribute__((ext_vector_type(4))) float f4v;

// swizzled element index for [64][64] bf16 matrix (rows 128B): XOR 16B slot by row&7
#define SWB(r, e) ((((r) << 6) + (e)) ^ (((r) & 7) << 3))

__device__ inline unsigned short bf16_rne(float x) {
    unsigned u = __float_as_uint(x);
    unsigned r = (u + 0x7FFFu + ((u >> 16) & 1u)) >> 16;
    return (unsigned short)r;
}
__device__ inline void split2(float x, unsigned short* h, unsigned short* l) {
    unsigned short hb = bf16_rne(x);
    *h = hb;
    float hf = __uint_as_float(((unsigned)hb) << 16);
    *l = bf16_rne(x - hf);
}

// K1: x [B][L][H] fp32 -> X-hi plane bf16 [B][H][4096]
__global__ __launch_bounds__(256) void split_transpose(const float* __restrict__ src,
                                                       unsigned short* __restrict__ dst) {
    __shared__ float tile[64][65];
    int b  = blockIdx.z;
    int h0 = blockIdx.x * 64;
    int l0 = blockIdx.y * 64;
    const float* s = src + (size_t)b * Lc * Hc;
    int tid = threadIdx.x;
#pragma unroll
    for (int it = 0; it < 4; it++) {
        int idx = tid + 256 * it;
        int r = idx >> 4, c4 = idx & 15;            // r = l-row, c4 = h-quad
        float4 v = *(const float4*)(s + (size_t)(l0 + r) * Hc + (h0 + 4 * c4));
        tile[r][4 * c4 + 0] = v.x;
        tile[r][4 * c4 + 1] = v.y;
        tile[r][4 * c4 + 2] = v.z;
        tile[r][4 * c4 + 3] = v.w;
    }
    __syncthreads();
#pragma unroll
    for (int it = 0; it < 8; it++) {
        int hh = it * 8 + (tid >> 5);               // h within tile
        int p  = tid & 31;                          // l-pair within tile
        float v0 = tile[2 * p + 0][hh];
        float v1 = tile[2 * p + 1][hh];
        unsigned hi = (unsigned)bf16_rne(v0) | ((unsigned)bf16_rne(v1) << 16);
        unsigned short* base = dst + (size_t)(b * Hc + h0 + hh) * 4096;
        *(unsigned*)(base + (l0 + 2 * p)) = hi;
    }
}

// K3: yT bf16 [B][H][L] -> out [B][L][H] fp32
__global__ __launch_bounds__(256) void untranspose_bf16(const unsigned short* __restrict__ src,
                                                        float* __restrict__ dst) {
    __shared__ float tile[64][65];   // [h_local][l_local]
    int b  = blockIdx.z;
    int h0 = blockIdx.x * 64;
    int l0 = blockIdx.y * 64;
    const unsigned short* s = src + (size_t)b * Hc * Lc;
    float* d = dst + (size_t)b * Lc * Hc;
    int tid = threadIdx.x;
#pragma unroll
    for (int it = 0; it < 8; it++) {
        int idx = tid + 256 * it;                  // 2048 dwords
        int hh = idx >> 5, dp = idx & 31;
        unsigned v = *(const unsigned*)(s + (size_t)(h0 + hh) * Lc + (l0 + 2 * dp));
        tile[hh][2 * dp]     = __uint_as_float((v & 0xffffu) << 16);
        tile[hh][2 * dp + 1] = __uint_as_float((v >> 16) << 16);
    }
    __syncthreads();
#pragma unroll
    for (int it = 0; it < 4; it++) {
        int idx = tid + 256 * it;
        int r = idx >> 4, c4 = idx & 15;           // r = l_local, c4 = h-quad
        f4v v;
        v.x = tile[4 * c4 + 0][r];
        v.y = tile[4 * c4 + 1][r];
        v.z = tile[4 * c4 + 2][r];
        v.w = tile[4 * c4 + 3][r];
        __builtin_nontemporal_store(v, (f4v*)(d + (size_t)(l0 + r) * Hc + (h0 + 4 * c4)));
    }
}

#define MFMA(a, b, c) __builtin_amdgcn_mfma_f32_16x16x32_bf16((a), (b), (c), 0, 0, 0)

// One block per h; 4 batches. Reads X-hi bf16 block; writes Y bf16 IN PLACE over
// the same block (X of batch b fully consumed before its Y store; prefetch of
// b+1 issued earlier; disjoint 8KB regions per (b,h) -> race-free).
__global__ __launch_bounds__(256, 4) void s4d_mfma8(
    const unsigned short* __restrict__ xpl,
    unsigned short* __restrict__ ypl,
    const float* __restrict__ log_dt,
    const float* __restrict__ log_A_real,
    const float* __restrict__ A_imag,
    const float* __restrict__ Cmat,
    const float* __restrict__ Dvec)
{
    __shared__ __align__(16) unsigned short WtH[4096];   // S = X*Wrev (hi)
    __shared__ __align__(16) unsigned short WpH[4096];   // carry powers (hi)
    __shared__ float Sscan[64 * 65];   // [mode-comp][chunk]; Kpart scratch; Y staging
    __shared__ float Ktap[64];
    __shared__ float cAr[NNc], cAi[NNc], c2R[NNc], c2I[NNc], cWSr[NNc], cWSi[NNc];

    const int tid = threadIdx.x;
    const int h   = blockIdx.x;
    const int w   = tid >> 6;
    const int l   = tid & 63;
    const int l15 = l & 15;
    const int grp = l >> 4;
    const int rowoff = (16 * w + l15) * 64;

    // early X frag load for b=0 (hides under table generation)
    s8v xh0, xh1;
    {
        const unsigned short* xb = xpl + (size_t)h * 4096;
        xh0 = *(const s8v*)(xb + rowoff + 8 * grp);
        xh1 = *(const s8v*)(xb + rowoff + 32 + 8 * grp);
    }

    // ---- per-mode constants (PRECISE: w^64 errors compound x63 in the scan) ----
    if (tid < NNc) {
        int n = tid;
        float dtv = expf(log_dt[h]);
        float Ar = -expf(log_A_real[h * NNc + n]);
        float Ai = A_imag[h * NNc + n];
        float ar = Ar * dtv, ai = Ai * dtv;
        cAr[n] = ar; cAi[n] = ai;
        float er = expf(ar), sn, cs;
        sincosf(ai, &sn, &cs);
        float numr = er * cs - 1.f, numi = er * sn;
        float inv = 1.f / (Ar * Ar + Ai * Ai);
        float fr = (numr * Ar + numi * Ai) * inv;
        float fi = (numi * Ar - numr * Ai) * inv;
        float Ccr = Cmat[(h * NNc + n) * 2 + 0];
        float Cci = Cmat[(h * NNc + n) * 2 + 1];
        c2R[n] = 2.f * (Ccr * fr - Cci * fi);
        c2I[n] = 2.f * (Ccr * fi + Cci * fr);
        float e64 = expf(64.f * ar), s64, c64;
        sincosf(64.f * ai, &s64, &c64);
        cWSr[n] = e64 * c64; cWSi[n] = e64 * s64;   // w^64
    }
    __syncthreads();

    // ---- Kpart (into Sscan scratch) + Wt + Wp generation (fast intrinsics) ----
    {
        int p = tid >> 2, q = tid & 3;
        float acc = 0.f;
#pragma unroll
        for (int i = 0; i < 8; i++) {
            int n = 8 * q + i;
            float fp = (float)p;
            float e = __expf(cAr[n] * fp);
            float sn = __sinf(cAi[n] * fp), cs = __cosf(cAi[n] * fp);
            acc += e * (c2R[n] * cs - c2I[n] * sn);
        }
        Sscan[p * 4 + q] = acc;
    }
#pragma unroll
    for (int m = 0; m < 2; m++) {
        int u = tid + 256 * m;
        int r = u >> 3, jc = u & 7;
        {   // Wt row r = out mode-comp: w_n^{63-j} (hi only)
            int n = r >> 1, im = r & 1;
            s8v hv;
#pragma unroll
            for (int i = 0; i < 8; i++) {
                float p = (float)(63 - (jc * 8 + i));
                float e = __expf(cAr[n] * p);
                float sn = __sinf(cAi[n] * p), cs = __cosf(cAi[n] * p);
                hv[i] = (short)bf16_rne(e * (im ? sn : cs));
            }
            *(s8v*)&WtH[SWB(r, jc * 8)] = hv;
        }
        {   // Wp row r = t: col c: Re(w^{t+1}) / -Im(w^{t+1})  (hi only)
            float p = (float)(r + 1);
            s8v hv;
#pragma unroll
            for (int i = 0; i < 8; i++) {
                int c = jc * 8 + i;
                int n = c >> 1;
                float e = __expf(cAr[n] * p);
                float sn = __sinf(cAi[n] * p), cs = __cosf(cAi[n] * p);
                hv[i] = (short)bf16_rne(e * ((c & 1) ? -sn : cs));
            }
            *(s8v*)&WpH[SWB(r, jc * 8)] = hv;
        }
    }
    __syncthreads();

    if (tid < 64) {
        float k = Sscan[tid * 4] + Sscan[tid * 4 + 1] + Sscan[tid * 4 + 2] + Sscan[tid * 4 + 3];
        if (tid == 0) k += Dvec[h];
        Ktap[tid] = k;
    }
    __syncthreads();

    // ---- Toeplitz B-fragments: batch-invariant -> registers (8 x s8v) ----
    s8v tf[4][2];
#pragma unroll
    for (int tj = 0; tj < 4; tj++) {
        int row = tj * 16 + l15;
#pragma unroll
        for (int hf = 0; hf < 2; hf++) {
            int kb = 32 * hf + 8 * grp;
            s8v v;
#pragma unroll
            for (int i = 0; i < 8; i++) {
                int idx = row - kb - i;
                int ic = idx < 0 ? 0 : idx;
                float kv = Ktap[ic];
                v[i] = (short)bf16_rne(idx < 0 ? 0.f : kv);
            }
            tf[tj][hf] = v;
        }
    }

    // ---- batch loop ----
#pragma unroll
    for (int b = 0; b < Bc; b++) {
        // prefetch next batch's X fragments (issued before this batch's Y store)
        s8v nh0, nh1;
        if (b < Bc - 1) {
            const unsigned short* xb = xpl + (size_t)((b + 1) * Hc + h) * 4096;
            nh0 = *(const s8v*)(xb + rowoff + 8 * grp);
            nh1 = *(const s8v*)(xb + rowoff + 32 + 8 * grp);
        }

        // Phase 1: S = X * Wrev. D rows = chunk s, cols = mode-comp m.
        f4v acc[4];
#pragma unroll
        for (int tj = 0; tj < 4; tj++) {
            int row = tj * 16 + l15;
            int i0 = SWB(row, 8 * grp);
            int i1 = SWB(row, 32 + 8 * grp);
            s8v bh0 = *(const s8v*)&WtH[i0];
            s8v bh1 = *(const s8v*)&WtH[i1];
            f4v a = {0.f, 0.f, 0.f, 0.f};
            a = MFMA(xh0, bh0, a);
            a = MFMA(xh1, bh1, a);
            acc[tj] = a;
        }
        // store S transposed: Sscan[m][s]
#pragma unroll
        for (int tj = 0; tj < 4; tj++) {
#pragma unroll
            for (int r2 = 0; r2 < 4; r2++) {
                Sscan[(tj * 16 + l15) * 65 + 16 * w + 4 * grp + r2] = acc[tj][r2];
            }
        }
        __syncthreads();   // (a)

        // ---- wave-parallel Kogge-Stone scan: wave w owns modes 8w..8w+7, lane = chunk ----
        {
            float Pr[8], Pi[8], qr[8], qi[8];
#pragma unroll
            for (int i = 0; i < 8; i++) {
                int m0 = (16 * w + 2 * i) * 65;
                Pr[i] = Sscan[m0 + l];
                Pi[i] = Sscan[m0 + 65 + l];
                int n = 8 * w + i;
                qr[i] = cWSr[n]; qi[i] = cWSi[n];
            }
#pragma unroll
            for (int d = 1; d < 64; d <<= 1) {
#pragma unroll
                for (int i = 0; i < 8; i++) {
                    float tr = __shfl_up(Pr[i], (unsigned)d, 64);
                    float ti = __shfl_up(Pi[i], (unsigned)d, 64);
                    if (l >= d) {
                        Pr[i] = fmaf(qr[i], tr, fmaf(-qi[i], ti, Pr[i]));
                        Pi[i] = fmaf(qr[i], ti, fmaf( qi[i], tr, Pi[i]));
                    }
                }
                if (d < 32) {
#pragma unroll
                    for (int i = 0; i < 8; i++) {
                        float nr = fmaf(qr[i], qr[i], -(qi[i] * qi[i]));
                        float ni = 2.f * qr[i] * qi[i];
                        qr[i] = nr; qi[i] = ni;
                    }
                }
            }
            // G_s = P_{s-1}; E = 2Cw (x) G
#pragma unroll
            for (int i = 0; i < 8; i++) {
                float Gr = __shfl_up(Pr[i], 1u, 64);
                float Gi = __shfl_up(Pi[i], 1u, 64);
                if (l == 0) { Gr = 0.f; Gi = 0.f; }
                int n = 8 * w + i;
                float cr = c2R[n], ci = c2I[n];
                float er = fmaf(cr, Gr, -(ci * Gi));
                float ei = fmaf(cr, Gi,  (ci * Gr));
                int m0 = (16 * w + 2 * i) * 65;
                Sscan[m0 + l]      = er;
                Sscan[m0 + 65 + l] = ei;
            }
        }
        __syncthreads();   // (b)

        // E fragments (hi-only bf16): A rows = chunk 16w+l15, k = mode-comp
        s8v eh0, eh1;
        {
            float ev[16];
#pragma unroll
            for (int i = 0; i < 8; i++)
                ev[i] = Sscan[(8 * grp + i) * 65 + 16 * w + l15];
#pragma unroll
            for (int i = 0; i < 8; i++)
                ev[8 + i] = Sscan[(32 + 8 * grp + i) * 65 + 16 * w + l15];
#pragma unroll
            for (int i = 0; i < 8; i++) {
                eh0[i] = (short)bf16_rne(ev[i]);
                eh1[i] = (short)bf16_rne(ev[8 + i]);
            }
        }
        __syncthreads();   // (c) — Sscan free for Y staging

        // Phase 3: Y = X*T + E*Wp -> stage fp32 into Sscan[s][t]
#pragma unroll
        for (int tj = 0; tj < 4; tj++) {
            int row = tj * 16 + l15;
            int i0 = SWB(row, 8 * grp);
            int i1 = SWB(row, 32 + 8 * grp);
            s8v ph0 = *(const s8v*)&WpH[i0];
            s8v ph1 = *(const s8v*)&WpH[i1];
            f4v a = {0.f, 0.f, 0.f, 0.f};
            a = MFMA(xh0, tf[tj][0], a);
            a = MFMA(xh1, tf[tj][1], a);
            a = MFMA(eh0, ph0, a);
            a = MFMA(eh1, ph1, a);
#pragma unroll
            for (int r2 = 0; r2 < 4; r2++) {
                Sscan[(16 * w + 4 * grp + r2) * 65 + tj * 16 + l15] = a[r2];
            }
        }
        __syncthreads();   // (d) — Y tile complete in LDS

        // stream Y out as bf16 IN PLACE over this (b,h) X block
        {
            unsigned short* yp = ypl + (size_t)(b * Hc + h) * 4096;
#pragma unroll
            for (int i = 0; i < 8; i++) {
                int p = tid + 256 * i;              // dword index 0..2047
                int s = p >> 5, tp = p & 31;
                float v0 = Sscan[s * 65 + 2 * tp];
                float v1 = Sscan[s * 65 + 2 * tp + 1];
                unsigned pk = (unsigned)bf16_rne(v0) | ((unsigned)bf16_rne(v1) << 16);
                *(unsigned*)(yp + 2 * p) = pk;
            }
        }
        __syncthreads();   // (e) — Sscan free for next batch

        if (b < Bc - 1) { xh0 = nh0; xh1 = nh1; }
    }
}

extern "C" void kernel_launch(void* const* d_in, const int* in_sizes, int n_in,
                              void* d_out, int out_size, void* d_ws, size_t ws_size,
                              hipStream_t stream) {
    const float* x          = (const float*)d_in[0];
    const float* log_dt     = (const float*)d_in[1];
    const float* log_A_real = (const float*)d_in[2];
    const float* A_imag     = (const float*)d_in[3];
    const float* Cmat       = (const float*)d_in[4];
    const float* Dvec       = (const float*)d_in[5];
    float* out = (float*)d_out;

    const size_t plane = (size_t)Bc * Hc * Lc;                // elements (bf16)
    const size_t need  = plane * sizeof(unsigned short);      // single plane = 32 MiB
    if (ws_size < need) return;

    unsigned short* xpl = (unsigned short*)d_ws;              // X-hi, then Y in place

    // x [B][L][H] -> X-hi bf16 plane [B][H][L]
    split_transpose<<<dim3(Hc / 64, Lc / 64, Bc), 256, 0, stream>>>(x, xpl);
    // fused SSM per h (all batches); Y bf16 overwrites X plane in place
    s4d_mfma8<<<Hc, 256, 0, stream>>>(xpl, xpl, log_dt, log_A_real, A_imag, Cmat, Dvec);
    // Y bf16 [B][H][L] -> out fp32 [B][L][H]
    untranspose_bf16<<<dim3(Hc / 64, Lc / 64, Bc), 256, 0, stream>>>(xpl, out);
}

// Round 11
// 62.412 us; speedup vs baseline: 6.2988x; 1.5382x over previous
//
#include <hip/hip_runtime.h>
#include <math.h>

#define Lc 4096
#define Hc 1024
#define Bc 4
#define NNc 32

typedef __attribute__((ext_vector_type(8))) short s8v;
typedef __attribute__((ext_vector_type(4))) float f4v;

// swizzled element index for [64][64] bf16 matrix (rows 128B): XOR 16B slot by row&7
#define SWB(r, e) ((((r) << 6) + (e)) ^ (((r) & 7) << 3))

__device__ inline unsigned short bf16_rne(float x) {
    unsigned u = __float_as_uint(x);
    unsigned r = (u + 0x7FFFu + ((u >> 16) & 1u)) >> 16;
    return (unsigned short)r;
}

// K1: x [B][L][H] fp32 -> X-hi plane bf16 [B][H][4096]
__global__ __launch_bounds__(256) void split_transpose(const float* __restrict__ src,
                                                       unsigned short* __restrict__ dst) {
    __shared__ float tile[64][65];
    int b  = blockIdx.z;
    int h0 = blockIdx.x * 64;
    int l0 = blockIdx.y * 64;
    const float* s = src + (size_t)b * Lc * Hc;
    int tid = threadIdx.x;
#pragma unroll
    for (int it = 0; it < 4; it++) {
        int idx = tid + 256 * it;
        int r = idx >> 4, c4 = idx & 15;            // r = l-row, c4 = h-quad
        float4 v = *(const float4*)(s + (size_t)(l0 + r) * Hc + (h0 + 4 * c4));
        tile[r][4 * c4 + 0] = v.x;
        tile[r][4 * c4 + 1] = v.y;
        tile[r][4 * c4 + 2] = v.z;
        tile[r][4 * c4 + 3] = v.w;
    }
    __syncthreads();
#pragma unroll
    for (int it = 0; it < 8; it++) {
        int hh = it * 8 + (tid >> 5);               // h within tile
        int p  = tid & 31;                          // l-pair within tile
        float v0 = tile[2 * p + 0][hh];
        float v1 = tile[2 * p + 1][hh];
        unsigned hi = (unsigned)bf16_rne(v0) | ((unsigned)bf16_rne(v1) << 16);
        unsigned short* base = dst + (size_t)(b * Hc + h0 + hh) * 4096;
        *(unsigned*)(base + (l0 + 2 * p)) = hi;
    }
}

// K3: yT bf16 [B][H][L] -> out [B][L][H] fp32
__global__ __launch_bounds__(256) void untranspose_bf16(const unsigned short* __restrict__ src,
                                                        float* __restrict__ dst) {
    __shared__ float tile[64][65];   // [h_local][l_local]
    int b  = blockIdx.z;
    int h0 = blockIdx.x * 64;
    int l0 = blockIdx.y * 64;
    const unsigned short* s = src + (size_t)b * Hc * Lc;
    float* d = dst + (size_t)b * Lc * Hc;
    int tid = threadIdx.x;
#pragma unroll
    for (int it = 0; it < 8; it++) {
        int idx = tid + 256 * it;                  // 2048 dwords
        int hh = idx >> 5, dp = idx & 31;
        unsigned v = *(const unsigned*)(s + (size_t)(h0 + hh) * Lc + (l0 + 2 * dp));
        tile[hh][2 * dp]     = __uint_as_float((v & 0xffffu) << 16);
        tile[hh][2 * dp + 1] = __uint_as_float((v >> 16) << 16);
    }
    __syncthreads();
#pragma unroll
    for (int it = 0; it < 4; it++) {
        int idx = tid + 256 * it;
        int r = idx >> 4, c4 = idx & 15;           // r = l_local, c4 = h-quad
        f4v v;
        v.x = tile[4 * c4 + 0][r];
        v.y = tile[4 * c4 + 1][r];
        v.z = tile[4 * c4 + 2][r];
        v.w = tile[4 * c4 + 3][r];
        __builtin_nontemporal_store(v, (f4v*)(d + (size_t)(l0 + r) * Hc + (h0 + 4 * c4)));
    }
}

#define MFMA(a, b, c) __builtin_amdgcn_mfma_f32_16x16x32_bf16((a), (b), (c), 0, 0, 0)

// One block per h; 4 batches. Register-space carry scan (no LDS scan round-trip).
// Phase-1 cols reordered m = im*32+n so each thread holds both complex comps of
// 2 modes x 4 chunks in acc. Y bf16 written directly to global, in place.
__global__ __launch_bounds__(256, 4) void s4d_mfma9(
    const unsigned short* __restrict__ xpl,
    unsigned short* __restrict__ ypl,
    const float* __restrict__ log_dt,
    const float* __restrict__ log_A_real,
    const float* __restrict__ A_imag,
    const float* __restrict__ Cmat,
    const float* __restrict__ Dvec)
{
    __shared__ __align__(16) unsigned short WtH[4096];   // phase-1 B (rows m=im*32+n)
    __shared__ __align__(16) unsigned short WpH[4096];   // carry powers (rows t, k=2n+im)
    __shared__ __align__(16) unsigned short TtH[4096];   // toeplitz taps (rows t, k=j)
    __shared__ __align__(16) unsigned short Elds[64 * 72]; // E bf16 [chunk][64 k]+8 pad
    __shared__ float WV[256];          // Kpart scratch, then wave carry totals
    __shared__ float Ktap[64];
    __shared__ float cAr[NNc], cAi[NNc], c2R[NNc], c2I[NNc], cWSr[NNc], cWSi[NNc];

    const int tid = threadIdx.x;
    const int h   = blockIdx.x;
    const int w   = tid >> 6;
    const int l   = tid & 63;
    const int l15 = l & 15;
    const int grp = l >> 4;
    const int rowoff = (16 * w + l15) * 64;

    // early X frag load for b=0 (hides under table generation)
    s8v xh0, xh1;
    {
        const unsigned short* xb = xpl + (size_t)h * 4096;
        xh0 = *(const s8v*)(xb + rowoff + 8 * grp);
        xh1 = *(const s8v*)(xb + rowoff + 32 + 8 * grp);
    }

    // ---- per-mode constants (PRECISE: w^64 errors compound in the scan) ----
    if (tid < NNc) {
        int n = tid;
        float dtv = expf(log_dt[h]);
        float Ar = -expf(log_A_real[h * NNc + n]);
        float Ai = A_imag[h * NNc + n];
        float ar = Ar * dtv, ai = Ai * dtv;
        cAr[n] = ar; cAi[n] = ai;
        float er = expf(ar), sn, cs;
        sincosf(ai, &sn, &cs);
        float numr = er * cs - 1.f, numi = er * sn;
        float inv = 1.f / (Ar * Ar + Ai * Ai);
        float fr = (numr * Ar + numi * Ai) * inv;
        float fi = (numi * Ar - numr * Ai) * inv;
        float Ccr = Cmat[(h * NNc + n) * 2 + 0];
        float Cci = Cmat[(h * NNc + n) * 2 + 1];
        c2R[n] = 2.f * (Ccr * fr - Cci * fi);
        c2I[n] = 2.f * (Ccr * fi + Cci * fr);
        float e64 = expf(64.f * ar), s64, c64;
        sincosf(64.f * ai, &s64, &c64);
        cWSr[n] = e64 * c64; cWSi[n] = e64 * s64;   // w^64
    }
    __syncthreads();   // bar0

    // ---- Kpart (into WV scratch) + Wt + Wp generation ----
    {
        int p = tid >> 2, q = tid & 3;
        float acc = 0.f;
#pragma unroll
        for (int i = 0; i < 8; i++) {
            int n = 8 * q + i;
            float fp = (float)p;
            float e = __expf(cAr[n] * fp);
            float sn = __sinf(cAi[n] * fp), cs = __cosf(cAi[n] * fp);
            acc += e * (c2R[n] * cs - c2I[n] * sn);
        }
        WV[p * 4 + q] = acc;
    }
#pragma unroll
    for (int m = 0; m < 2; m++) {
        int u = tid + 256 * m;
        int r = u >> 3, jc = u & 7;
        {   // Wt row r = mode-comp m' = im*32+n: w_n^{63-j}, comp by im
            int n = r & 31, im = r >> 5;
            s8v hv;
#pragma unroll
            for (int i = 0; i < 8; i++) {
                float p = (float)(63 - (jc * 8 + i));
                float e = __expf(cAr[n] * p);
                float sn = __sinf(cAi[n] * p), cs = __cosf(cAi[n] * p);
                hv[i] = (short)bf16_rne(e * (im ? sn : cs));
            }
            *(s8v*)&WtH[SWB(r, jc * 8)] = hv;
        }
        {   // Wp row r = t: col c (k=2n+im): Re(w^{t+1}) / -Im(w^{t+1})
            float p = (float)(r + 1);
            s8v hv;
#pragma unroll
            for (int i = 0; i < 8; i++) {
                int c = jc * 8 + i;
                int n = c >> 1;
                float e = __expf(cAr[n] * p);
                float sn = __sinf(cAi[n] * p), cs = __cosf(cAi[n] * p);
                hv[i] = (short)bf16_rne(e * ((c & 1) ? -sn : cs));
            }
            *(s8v*)&WpH[SWB(r, jc * 8)] = hv;
        }
    }
    __syncthreads();   // bar1

    if (tid < 64) {
        float k = WV[tid * 4] + WV[tid * 4 + 1] + WV[tid * 4 + 2] + WV[tid * 4 + 3];
        if (tid == 0) k += Dvec[h];
        Ktap[tid] = k;
    }
    __syncthreads();   // bar2

    // ---- TtH table: row t, k=j: K[t-j] ----
#pragma unroll
    for (int m = 0; m < 2; m++) {
        int u = tid + 256 * m;
        int r = u >> 3, jc = u & 7;
        s8v hv;
#pragma unroll
        for (int i = 0; i < 8; i++) {
            int j = jc * 8 + i;
            hv[i] = (short)bf16_rne((j <= r) ? Ktap[r - j] : 0.f);
        }
        *(s8v*)&TtH[SWB(r, jc * 8)] = hv;
    }

    // ---- per-thread scan constants: modes n1=l15, n2=16+l15 ----
    float qR[2], qI[2], q4R[2], q4I[2], qgR[2], qgI[2], q16R[2], q16I[2], cwR[2], cwI[2];
#pragma unroll
    for (int md = 0; md < 2; md++) {
        int n = md * 16 + l15;
        float qr = cWSr[n], qi = cWSi[n];
        float q2r = fmaf(qr, qr, -(qi * qi)),    q2i = 2.f * qr * qi;
        float q4r = fmaf(q2r, q2r, -(q2i * q2i)), q4i = 2.f * q2r * q2i;
        float q8r = fmaf(q4r, q4r, -(q4i * q4i)), q8i = 2.f * q4r * q4i;
        float q16r = fmaf(q8r, q8r, -(q8i * q8i)), q16i = 2.f * q8r * q8i;
        float q12r = fmaf(q8r, q4r, -(q8i * q4i)), q12i = fmaf(q8r, q4i, q8i * q4r);
        qR[md] = qr; qI[md] = qi;
        q4R[md] = q4r; q4I[md] = q4i;
        qgR[md] = (grp == 0) ? 1.f : (grp == 1) ? q4r : (grp == 2) ? q8r : q12r;
        qgI[md] = (grp == 0) ? 0.f : (grp == 1) ? q4i : (grp == 2) ? q8i : q12i;
        q16R[md] = q16r; q16I[md] = q16i;
        cwR[md] = c2R[n]; cwI[md] = c2I[n];
    }
    __syncthreads();   // bar3

    // ---- batch loop (2 barriers per batch) ----
#pragma unroll
    for (int b = 0; b < Bc; b++) {
        s8v nh0, nh1;
        if (b < Bc - 1) {
            const unsigned short* xb = xpl + (size_t)((b + 1) * Hc + h) * 4096;
            nh0 = *(const s8v*)(xb + rowoff + 8 * grp);
            nh1 = *(const s8v*)(xb + rowoff + 32 + 8 * grp);
        }

        // Phase 1: S = X * Wrev. D rows = chunk, cols m = im*32+n.
        // acc[0]=Re n1, acc[1]=Re n2, acc[2]=Im n1, acc[3]=Im n2 (per r2 chunk).
        f4v acc[4];
#pragma unroll
        for (int tj = 0; tj < 4; tj++) {
            int row = tj * 16 + l15;
            s8v bh0 = *(const s8v*)&WtH[SWB(row, 8 * grp)];
            s8v bh1 = *(const s8v*)&WtH[SWB(row, 32 + 8 * grp)];
            f4v a = {0.f, 0.f, 0.f, 0.f};
            a = MFMA(xh0, bh0, a);
            a = MFMA(xh1, bh1, a);
            acc[tj] = a;
        }

        // ---- register-space carry scan ----
        float exr[2][4], exi[2][4], gcr[2], gci[2];
#pragma unroll
        for (int md = 0; md < 2; md++) {
            float qr = qR[md], qi = qI[md];
            float e1r = acc[md][0],                       e1i = acc[md + 2][0];
            float e2r = fmaf(qr, e1r, fmaf(-qi, e1i, acc[md][1]));
            float e2i = fmaf(qr, e1i, fmaf( qi, e1r, acc[md + 2][1]));
            float e3r = fmaf(qr, e2r, fmaf(-qi, e2i, acc[md][2]));
            float e3i = fmaf(qr, e2i, fmaf( qi, e2r, acc[md + 2][2]));
            float tr  = fmaf(qr, e3r, fmaf(-qi, e3i, acc[md][3]));
            float ti  = fmaf(qr, e3i, fmaf( qi, e3r, acc[md + 2][3]));
            exr[md][0] = 0.f; exi[md][0] = 0.f;
            exr[md][1] = e1r; exi[md][1] = e1i;
            exr[md][2] = e2r; exi[md][2] = e2i;
            exr[md][3] = e3r; exi[md][3] = e3i;
            float t1r = __shfl_up(tr, 16u, 64), t1i = __shfl_up(ti, 16u, 64);
            float t2r = __shfl_up(tr, 32u, 64), t2i = __shfl_up(ti, 32u, 64);
            float t3r = __shfl_up(tr, 48u, 64), t3i = __shfl_up(ti, 48u, 64);
            if (grp < 1) { t1r = 0.f; t1i = 0.f; }
            if (grp < 2) { t2r = 0.f; t2i = 0.f; }
            if (grp < 3) { t3r = 0.f; t3i = 0.f; }
            float q4r = q4R[md], q4i = q4I[md];
            float q8r = fmaf(q4r, q4r, -(q4i * q4i)), q8i = 2.f * q4r * q4i;
            float gr = t1r, gi = t1i;
            gr = fmaf(q4r, t2r, fmaf(-q4i, t2i, gr));
            gi = fmaf(q4r, t2i, fmaf( q4i, t2r, gi));
            gr = fmaf(q8r, t3r, fmaf(-q8i, t3i, gr));
            gi = fmaf(q8r, t3i, fmaf( q8i, t3r, gi));
            gcr[md] = gr; gci[md] = gi;
            // wave-inclusive total (valid at grp==3): Wv = q4*gc + T
            float wvr = fmaf(q4r, gr, fmaf(-q4i, gi, tr));
            float wvi = fmaf(q4r, gi, fmaf( q4i, gr, ti));
            if (l >= 48) {
                int n = md * 16 + l15;
                WV[w * 64 + 2 * n]     = wvr;
                WV[w * 64 + 2 * n + 1] = wvi;
            }
        }
        __syncthreads();   // s1 — WV totals visible

        // finish scan: wave carry, cin, G, E -> Elds (packed bf16)
#pragma unroll
        for (int md = 0; md < 2; md++) {
            int n = md * 16 + l15;
            float wcr = 0.f, wci = 0.f;
            if (w >= 1) {
                wcr = WV[(w - 1) * 64 + 2 * n];
                wci = WV[(w - 1) * 64 + 2 * n + 1];
            }
            if (w >= 2) {
                float vr = WV[(w - 2) * 64 + 2 * n], vi = WV[(w - 2) * 64 + 2 * n + 1];
                wcr = fmaf(q16R[md], vr, fmaf(-q16I[md], vi, wcr));
                wci = fmaf(q16R[md], vi, fmaf( q16I[md], vr, wci));
            }
            if (w >= 3) {
                float q32r = fmaf(q16R[md], q16R[md], -(q16I[md] * q16I[md]));
                float q32i = 2.f * q16R[md] * q16I[md];
                float vr = WV[(w - 3) * 64 + 2 * n], vi = WV[(w - 3) * 64 + 2 * n + 1];
                wcr = fmaf(q32r, vr, fmaf(-q32i, vi, wcr));
                wci = fmaf(q32r, vi, fmaf( q32i, vr, wci));
            }
            // cin = gc + q4^grp * wc
            float cir = fmaf(qgR[md], wcr, fmaf(-qgI[md], wci, gcr[md]));
            float cii = fmaf(qgR[md], wci, fmaf( qgI[md], wcr, gci[md]));
            // q powers for r2 offset
            float qr = qR[md], qi = qI[md];
            float q2r = fmaf(qr, qr, -(qi * qi)),  q2i = 2.f * qr * qi;
            float q3r = fmaf(q2r, qr, -(q2i * qi)), q3i = fmaf(q2r, qi, q2i * qr);
            float pr[4] = {1.f, qr, q2r, q3r};
            float pi[4] = {0.f, qi, q2i, q3i};
#pragma unroll
            for (int r2 = 0; r2 < 4; r2++) {
                float Gr2 = fmaf(pr[r2], cir, fmaf(-pi[r2], cii, exr[md][r2]));
                float Gi2 = fmaf(pr[r2], cii, fmaf( pi[r2], cir, exi[md][r2]));
                float Er2 = fmaf(cwR[md], Gr2, -(cwI[md] * Gi2));
                float Ei2 = fmaf(cwR[md], Gi2,  (cwI[md] * Gr2));
                unsigned pk = (unsigned)bf16_rne(Er2) | ((unsigned)bf16_rne(Ei2) << 16);
                int chunk = 16 * w + 4 * grp + r2;
                *(unsigned*)&Elds[chunk * 72 + 2 * n] = pk;
            }
        }
        __syncthreads();   // s2 — Elds complete

        // Phase 3: Y = X*T + E*Wp, direct global bf16 stores
        s8v ee0 = *(const s8v*)&Elds[(16 * w + l15) * 72 + 8 * grp];
        s8v ee1 = *(const s8v*)&Elds[(16 * w + l15) * 72 + 32 + 8 * grp];
        unsigned short* yp = ypl + (size_t)(b * Hc + h) * 4096;
#pragma unroll
        for (int tj = 0; tj < 4; tj++) {
            int row = tj * 16 + l15;
            int i0 = SWB(row, 8 * grp);
            int i1 = SWB(row, 32 + 8 * grp);
            s8v th0 = *(const s8v*)&TtH[i0];
            s8v th1 = *(const s8v*)&TtH[i1];
            s8v ph0 = *(const s8v*)&WpH[i0];
            s8v ph1 = *(const s8v*)&WpH[i1];
            f4v a = {0.f, 0.f, 0.f, 0.f};
            a = MFMA(xh0, th0, a);
            a = MFMA(xh1, th1, a);
            a = MFMA(ee0, ph0, a);
            a = MFMA(ee1, ph1, a);
#pragma unroll
            for (int r2 = 0; r2 < 4; r2++) {
                int chunk = 16 * w + 4 * grp + r2;
                yp[chunk * 64 + row] = bf16_rne(a[r2]);
            }
        }

        if (b < Bc - 1) { xh0 = nh0; xh1 = nh1; }
    }
}

extern "C" void kernel_launch(void* const* d_in, const int* in_sizes, int n_in,
                              void* d_out, int out_size, void* d_ws, size_t ws_size,
                              hipStream_t stream) {
    const float* x          = (const float*)d_in[0];
    const float* log_dt     = (const float*)d_in[1];
    const float* log_A_real = (const float*)d_in[2];
    const float* A_imag     = (const float*)d_in[3];
    const float* Cmat       = (const float*)d_in[4];
    const float* Dvec       = (const float*)d_in[5];
    float* out = (float*)d_out;

    const size_t plane = (size_t)Bc * Hc * Lc;                // elements (bf16)
    const size_t need  = plane * sizeof(unsigned short);      // single plane = 32 MiB
    if (ws_size < need) return;

    unsigned short* xpl = (unsigned short*)d_ws;              // X-hi, then Y in place

    // x [B][L][H] -> X-hi bf16 plane [B][H][L]
    split_transpose<<<dim3(Hc / 64, Lc / 64, Bc), 256, 0, stream>>>(x, xpl);
    // fused SSM per h (all batches); Y bf16 overwrites X plane in place
    s4d_mfma9<<<Hc, 256, 0, stream>>>(xpl, xpl, log_dt, log_A_real, A_imag, Cmat, Dvec);
    // Y bf16 [B][H][L] -> out fp32 [B][L][H]
    untranspose_bf16<<<dim3(Hc / 64, Lc / 64, Bc), 256, 0, stream>>>(xpl, out);
}